// Round 4
// baseline (605.048 us; speedup 1.0000x reference)
//
#include <hip/hip_runtime.h>
#include <hip/hip_bf16.h>

typedef __attribute__((ext_vector_type(8))) short short8;
typedef __attribute__((ext_vector_type(4))) float floatx4;
typedef __attribute__((ext_vector_type(4))) unsigned short ushort4_t;

#define B_    8
#define S_    8192
#define D_    512
#define E_    16
#define DFF_  512
#define KROW_ 1024   // tokens per expert (capacity)

__device__ __forceinline__ float bf2f(unsigned short u) {
    return __uint_as_float(((unsigned int)u) << 16);
}
__device__ __forceinline__ unsigned short f2bf(float f) {
    unsigned int u = __float_as_uint(f);
    u += 0x7FFFu + ((u >> 16) & 1u);
    return (unsigned short)(u >> 16);
}
__device__ __forceinline__ float gelu_tanh(float v) {
    // jax.nn.gelu(approximate=True): 0.5*x*(1+tanh(z)) == x*sigmoid(2z) exactly.
    const float t = v * fmaf(0.0713548065f, v * v, 1.5957691216057308f);
    return v * __builtin_amdgcn_rcpf(1.0f + __expf(-t));
}

#define GLD16(g, l) __builtin_amdgcn_global_load_lds( \
    (const __attribute__((address_space(1))) void*)(g), \
    (__attribute__((address_space(3))) void*)(l), 16, 0, 0)

// ---------------------------------------------------------------------------
// x fp32 -> xb bf16 (flat, coalesced, 16B stores). Fully parallel streaming
// kernel — deliberately NOT fused into the router (occupancy there is capped).
// ---------------------------------------------------------------------------
__global__ __launch_bounds__(256) void cvt_x_k(
    const float* __restrict__ x, unsigned short* __restrict__ xb, int n8)
{
    int i = blockIdx.x * 256 + threadIdx.x;
    if (i >= n8) return;
    float4 va = ((const float4*)x)[2 * i];
    float4 vb = ((const float4*)x)[2 * i + 1];
    short8 o;
    o[0] = (short)f2bf(va.x); o[1] = (short)f2bf(va.y);
    o[2] = (short)f2bf(va.z); o[3] = (short)f2bf(va.w);
    o[4] = (short)f2bf(vb.x); o[5] = (short)f2bf(vb.y);
    o[6] = (short)f2bf(vb.z); o[7] = (short)f2bf(vb.w);
    ((short8*)xb)[i] = o;
}

// ---------------------------------------------------------------------------
// w1[e][D][DFF] fp32 -> w1t[e][DFF][D] bf16 ; w2[e][DFF][D] fp32 -> w2t[e][D][DFF] bf16
// ---------------------------------------------------------------------------
__global__ __launch_bounds__(256) void transpose_w_k(
    const float* __restrict__ w1, const float* __restrict__ w2,
    unsigned short* __restrict__ w1t, unsigned short* __restrict__ w2t)
{
    __shared__ unsigned short tile[32][33];
    const int e = blockIdx.z & 15;
    const float*    src = (blockIdx.z < 16) ? w1 : w2;
    unsigned short* dst = (blockIdx.z < 16) ? w1t : w2t;
    const int x0 = blockIdx.x * 32, y0 = blockIdx.y * 32;
    const int tx = threadIdx.x, ty = threadIdx.y;   // block (32,8)
    const size_t base = (size_t)e * 512 * 512;
#pragma unroll
    for (int i = 0; i < 4; ++i)
        tile[ty + 8 * i][tx] = f2bf(src[base + (size_t)(y0 + ty + 8 * i) * 512 + x0 + tx]);
    __syncthreads();
#pragma unroll
    for (int i = 0; i < 4; ++i)
        dst[base + (size_t)(x0 + ty + 8 * i) * 512 + y0 + tx] = tile[tx][ty + 8 * i];
}

// ---------------------------------------------------------------------------
// Router, 8 lanes per token (each lane owns experts {2*sub, 2*sub+1}).
// 512 thr/block, 1024 blocks -> 32 waves/CU (was 1 wave/SIMD: latency-starved).
// NUMERICS: per-expert fp32 fma chain over d is the EXACT same sequential
// order as the 1-thread/token version; max over 16 is order-exact; the sum of
// exps is gathered via shfl and accumulated in the original e=0..15 order ->
// aff is BITWISE IDENTICAL (zero top-k selection risk).
// ---------------------------------------------------------------------------
__global__ __launch_bounds__(512) void router_k(
    const float* __restrict__ x,   // [B,S,D]
    const float* __restrict__ gw,  // [D,E]
    float* __restrict__ aff)       // [B,E,S]
{
    __shared__ float gws[D_ * E_];   // 32 KB
    const int t = threadIdx.x;
    for (int i = t; i < D_ * E_; i += 512) gws[i] = gw[i];
    __syncthreads();

    const int lane = t & 63;
    const int sub  = lane & 7;                    // expert pair id
    const int tok  = blockIdx.x * 64 + (t >> 3);
    const float4* xr = (const float4*)(x + (size_t)tok * D_);

    float acc0 = 0.f, acc1 = 0.f;
#pragma unroll 4
    for (int d8 = 0; d8 < D_ / 8; ++d8) {
        const float4 va = xr[2 * d8];
        const float4 vb = xr[2 * d8 + 1];
#pragma unroll
        for (int q = 0; q < 8; ++q) {
            const float xv = (q < 4) ? (&va.x)[q] : (&vb.x)[q - 4];
            // conflict-free LDS: 8 distinct float2 addrs per group, broadcast across tokens
            const float2 gv = *(const float2*)&gws[(d8 * 8 + q) * E_ + 2 * sub];
            acc0 = fmaf(xv, gv.x, acc0);
            acc1 = fmaf(xv, gv.y, acc1);
        }
    }

    const int base = lane & 56;                   // first lane of my 8-lane group
    // gather all 16 accumulators (lane base+i holds experts 2i, 2i+1)
    float accs[E_];
#pragma unroll
    for (int i = 0; i < 8; ++i) {
        accs[2 * i]     = __shfl(acc0, base + i);
        accs[2 * i + 1] = __shfl(acc1, base + i);
    }
    float mx = accs[0];
#pragma unroll
    for (int e = 1; e < E_; ++e) mx = fmaxf(mx, accs[e]);   // order-exact
    const float e0v = expf(acc0 - mx);
    const float e1v = expf(acc1 - mx);
    float sm = 0.f;
#pragma unroll
    for (int i = 0; i < 8; ++i) {                 // sum in original e=0..15 order
        sm += __shfl(e0v, base + i);
        sm += __shfl(e1v, base + i);
    }
    const float inv = 1.f / sm;
    const int b = tok >> 13, s = tok & (S_ - 1);
    aff[((size_t)b * E_ + 2 * sub) * S_ + s]     = e0v * inv;
    aff[((size_t)b * E_ + 2 * sub + 1) * S_ + s] = e1v * inv;
}

// ---------------------------------------------------------------------------
// Top-k per (b,e): exact k-th-largest via 4-level MSB radix select (8/8/8/7
// bits), stable ties by ascending index. 1024 threads, keys LDS-resident.
// Single-wave shfl suffix scan (no barriers), hierarchical tie-rank scan.
// ---------------------------------------------------------------------------
__global__ __launch_bounds__(1024) void topk_k(
    const float* __restrict__ aff, int* __restrict__ idxb, int* __restrict__ map)
{
    __shared__ unsigned int keys[S_];        // 32 KB
    __shared__ unsigned int hist[4][257];    // 4 privatized copies (+pad)
    __shared__ unsigned int wsum[16];
    __shared__ unsigned int sh_b, sh_above, sh_ctr;

    const int b = blockIdx.x >> 4, e = blockIdx.x & 15;
    const float* a = aff + ((size_t)b * E_ + e) * S_;
    const int t = threadIdx.x;
    const int lane = t & 63, wid = t >> 6;

    for (int i = t; i < S_; i += 1024) keys[i] = __float_as_uint(a[i]);
    if (t == 0) sh_ctr = 0;
    hist[t >> 8][t & 255] = 0;               // zero for level 0
    __syncthreads();

    unsigned int prefix = 0, need = KROW_;
#pragma unroll
    for (int lev = 0; lev < 4; ++lev) {
        const int shift = (lev == 0) ? 23 : (lev == 1) ? 15 : (lev == 2) ? 7 : 0;
        const unsigned int fmask = (lev == 3) ? 127u : 255u;
        const int sw = shift + ((lev == 3) ? 7 : 8);
        const unsigned int mask_hi = 0xFFFFFFFFu << sw;

        for (int i = t; i < S_; i += 1024) {
            unsigned int k = keys[i];
            if ((k & mask_hi) == prefix)
                atomicAdd(&hist[t >> 8][(k >> shift) & fmask], 1u);
        }
        __syncthreads();

        // single-wave suffix scan over 256 bins: lane l owns bins 4l..4l+3
        if (t < 64) {
            unsigned int s0 = 0, s1 = 0, s2 = 0, s3 = 0;
#pragma unroll
            for (int c = 0; c < 4; ++c) {
                s0 += hist[c][4 * t + 0]; s1 += hist[c][4 * t + 1];
                s2 += hist[c][4 * t + 2]; s3 += hist[c][4 * t + 3];
            }
            const unsigned int v3 = s3, v2 = s2 + v3, v1 = s1 + v2, v0 = s0 + v1;
            const unsigned int G = v0;
            unsigned int T = v0;
#pragma unroll
            for (int off = 1; off < 64; off <<= 1) {
                unsigned int u = (unsigned int)__shfl_down((int)T, off);
                if (lane + off < 64) T += u;
            }
            const unsigned int R = T - G;
            unsigned int Sv[5];
            Sv[0] = T; Sv[1] = v1 + R; Sv[2] = v2 + R; Sv[3] = v3 + R; Sv[4] = R;
#pragma unroll
            for (int k2 = 0; k2 < 4; ++k2)
                if (Sv[k2] >= need && Sv[k2 + 1] < need) {
                    sh_b = (unsigned int)(4 * t + k2);
                    sh_above = Sv[k2 + 1];
                }
        }
        __syncthreads();
        prefix |= sh_b << shift;
        need   -= sh_above;
        if (lev < 3) hist[t >> 8][t & 255] = 0;
        __syncthreads();
    }

    const unsigned int thr = prefix;        // exact k-th largest key
    const unsigned int need_eq = need;      // # ties (==thr) to keep
    const unsigned int m_gt = KROW_ - need_eq;

    int* idxg = idxb + ((size_t)b * E_ + e) * KROW_;
    for (int i = t; i < S_; i += 1024) {
        unsigned int k = keys[i];
        if (k > thr) {
            unsigned int slot = atomicAdd(&sh_ctr, 1u);
            idxg[slot] = i;
            map[((size_t)b * S_ + i) * E_ + e] = (int)slot;
        }
    }
    // stable tie ranking: hierarchical scan of per-thread tie counts
    unsigned int lt = 0;
    const int i0 = t * 8;
#pragma unroll
    for (int q = 0; q < 8; ++q) lt += (keys[i0 + q] == thr);
    unsigned int incl = lt;
#pragma unroll
    for (int off = 1; off < 64; off <<= 1) {
        unsigned int u = (unsigned int)__shfl_up((int)incl, off);
        if (lane >= off) incl += u;
    }
    if (lane == 63) wsum[wid] = incl;
    __syncthreads();
    if (t < 16) {
        unsigned int wv = wsum[t];
        unsigned int ex = wv;
#pragma unroll
        for (int off = 1; off < 16; off <<= 1) {
            unsigned int u = (unsigned int)__shfl_up((int)ex, off);
            if (lane >= off) ex += u;
        }
        wsum[t] = ex - wv;
    }
    __syncthreads();
    unsigned int r = (incl - lt) + wsum[wid];
#pragma unroll
    for (int q = 0; q < 8; ++q) {
        if (keys[i0 + q] == thr) {
            if (r < need_eq) {
                idxg[m_gt + r] = i0 + q;
                map[((size_t)b * S_ + (i0 + q)) * E_ + e] = (int)(m_gt + r);
            }
            r++;
        }
    }
}

// ---------------------------------------------------------------------------
// GEMM1: h[bl,e,j,:] = gelu( xb[b, idx[b,e,j], :] @ w1t[e]^T + b1[e] )
// 128x128 tile, BK=32, double-buffered LDS with prefetch-before-compute.
// ---------------------------------------------------------------------------
__global__ __launch_bounds__(256) void gemm1_k(
    const unsigned short* __restrict__ xb,   // [B,S,D] bf16
    const unsigned short* __restrict__ w1t,  // [E,DFF,D] bf16 (B^T: [N,K])
    const float* __restrict__ b1,            // [E,DFF] fp32
    const int* __restrict__ idxb,            // [B,E,KROW]
    unsigned short* __restrict__ h,          // [bchunk,E,KROW,DFF] bf16
    int b_base)
{
    __shared__ unsigned short As[2][128 * 32];
    __shared__ unsigned short Bs[2][128 * 32];
    const int e  = blockIdx.z & 15;
    const int bl = blockIdx.z >> 4;
    const int b  = b_base + bl;
    const int m0 = blockIdx.x * 128;
    const int n0 = blockIdx.y * 128;
    const int t = threadIdx.x;
    const int w = t >> 6, l = t & 63;
    const int r0 = t >> 2, c0 = (t & 3) * 8;

    const int* idxg = idxb + ((size_t)b * E_ + e) * KROW_;
    const int s0 = idxg[m0 + r0];
    const int s1 = idxg[m0 + 64 + r0];
    const unsigned short* a0 = xb + ((size_t)b * S_ + s0) * D_ + c0;
    const unsigned short* a1 = xb + ((size_t)b * S_ + s1) * D_ + c0;
    const unsigned short* g0 = w1t + ((size_t)e * DFF_ + n0 + r0) * D_ + c0;
    const unsigned short* g1 = w1t + ((size_t)e * DFF_ + n0 + 64 + r0) * D_ + c0;

    floatx4 acc[4][4];
#pragma unroll
    for (int i = 0; i < 4; ++i)
#pragma unroll
        for (int j = 0; j < 4; ++j) acc[i][j] = (floatx4){0.f, 0.f, 0.f, 0.f};

    const int wm = (w >> 1) * 64, wn = (w & 1) * 64;
    const int lane15 = l & 15, lk = (l >> 4) * 8;

    {
        unsigned short* asd = &As[0][w * 512];
        unsigned short* bsd = &Bs[0][w * 512];
        GLD16(a0, asd); GLD16(a1, asd + 2048);
        GLD16(g0, bsd); GLD16(g1, bsd + 2048);
    }
    __syncthreads();

#pragma unroll
    for (int kt = 0; kt < D_ / 32; ++kt) {
        const int cur = kt & 1;
        if (kt + 1 < D_ / 32) {
            const int k1 = (kt + 1) * 32;
            unsigned short* asd = &As[cur ^ 1][w * 512];
            unsigned short* bsd = &Bs[cur ^ 1][w * 512];
            GLD16(a0 + k1, asd); GLD16(a1 + k1, asd + 2048);
            GLD16(g0 + k1, bsd); GLD16(g1 + k1, bsd + 2048);
        }
        short8 af[4], bf[4];
#pragma unroll
        for (int i = 0; i < 4; ++i) af[i] = *(const short8*)&As[cur][(wm + i * 16 + lane15) * 32 + lk];
#pragma unroll
        for (int j = 0; j < 4; ++j) bf[j] = *(const short8*)&Bs[cur][(wn + j * 16 + lane15) * 32 + lk];
#pragma unroll
        for (int i = 0; i < 4; ++i)
#pragma unroll
            for (int j = 0; j < 4; ++j)
                acc[i][j] = __builtin_amdgcn_mfma_f32_16x16x32_bf16(af[i], bf[j], acc[i][j], 0, 0, 0);
        __syncthreads();
    }

    float biasv[4];
#pragma unroll
    for (int j = 0; j < 4; ++j) biasv[j] = b1[e * DFF_ + n0 + wn + j * 16 + lane15];

    const size_t hbase = ((size_t)bl * E_ + e) * KROW_ * DFF_;
#pragma unroll
    for (int i = 0; i < 4; ++i)
#pragma unroll
        for (int j = 0; j < 4; ++j) {
            const int n = n0 + wn + j * 16 + lane15;
#pragma unroll
            for (int r = 0; r < 4; ++r) {
                const int m = m0 + wm + i * 16 + (l >> 4) * 4 + r;
                h[hbase + (size_t)m * DFF_ + n] = f2bf(gelu_tanh(acc[i][j][r] + biasv[j]));
            }
        }
}

// ---------------------------------------------------------------------------
// GEMM2: ex[bl,e,j,:] = h[bl,e,j,:] @ w2t[e]^T + b2[e]   (same dbuf pipeline)
// ---------------------------------------------------------------------------
__global__ __launch_bounds__(256) void gemm2_k(
    const unsigned short* __restrict__ h,    // [bchunk,E,KROW,DFF] bf16
    const unsigned short* __restrict__ w2t,  // [E,D,DFF] bf16 (B^T: [N,K])
    const float* __restrict__ b2,            // [E,D] fp32
    unsigned short* __restrict__ ex)         // [bchunk,E,KROW,D] bf16
{
    __shared__ unsigned short As[2][128 * 32];
    __shared__ unsigned short Bs[2][128 * 32];
    const int e  = blockIdx.z & 15;
    const int bl = blockIdx.z >> 4;
    const int m0 = blockIdx.x * 128;
    const int n0 = blockIdx.y * 128;
    const int t = threadIdx.x;
    const int w = t >> 6, l = t & 63;
    const int r0 = t >> 2, c0 = (t & 3) * 8;

    const unsigned short* a0 = h + (((size_t)bl * E_ + e) * KROW_ + m0 + r0) * DFF_ + c0;
    const unsigned short* a1 = h + (((size_t)bl * E_ + e) * KROW_ + m0 + 64 + r0) * DFF_ + c0;
    const unsigned short* g0 = w2t + ((size_t)e * D_ + n0 + r0) * DFF_ + c0;
    const unsigned short* g1 = w2t + ((size_t)e * D_ + n0 + 64 + r0) * DFF_ + c0;

    floatx4 acc[4][4];
#pragma unroll
    for (int i = 0; i < 4; ++i)
#pragma unroll
        for (int j = 0; j < 4; ++j) acc[i][j] = (floatx4){0.f, 0.f, 0.f, 0.f};

    const int wm = (w >> 1) * 64, wn = (w & 1) * 64;
    const int lane15 = l & 15, lk = (l >> 4) * 8;

    {
        unsigned short* asd = &As[0][w * 512];
        unsigned short* bsd = &Bs[0][w * 512];
        GLD16(a0, asd); GLD16(a1, asd + 2048);
        GLD16(g0, bsd); GLD16(g1, bsd + 2048);
    }
    __syncthreads();

#pragma unroll
    for (int kt = 0; kt < DFF_ / 32; ++kt) {
        const int cur = kt & 1;
        if (kt + 1 < DFF_ / 32) {
            const int k1 = (kt + 1) * 32;
            unsigned short* asd = &As[cur ^ 1][w * 512];
            unsigned short* bsd = &Bs[cur ^ 1][w * 512];
            GLD16(a0 + k1, asd); GLD16(a1 + k1, asd + 2048);
            GLD16(g0 + k1, bsd); GLD16(g1 + k1, bsd + 2048);
        }
        short8 af[4], bf[4];
#pragma unroll
        for (int i = 0; i < 4; ++i) af[i] = *(const short8*)&As[cur][(wm + i * 16 + lane15) * 32 + lk];
#pragma unroll
        for (int j = 0; j < 4; ++j) bf[j] = *(const short8*)&Bs[cur][(wn + j * 16 + lane15) * 32 + lk];
#pragma unroll
        for (int i = 0; i < 4; ++i)
#pragma unroll
            for (int j = 0; j < 4; ++j)
                acc[i][j] = __builtin_amdgcn_mfma_f32_16x16x32_bf16(af[i], bf[j], acc[i][j], 0, 0, 0);
        __syncthreads();
    }

    float biasv[4];
#pragma unroll
    for (int j = 0; j < 4; ++j) biasv[j] = b2[e * D_ + n0 + wn + j * 16 + lane15];

    const size_t xbase = ((size_t)bl * E_ + e) * KROW_ * D_;
#pragma unroll
    for (int i = 0; i < 4; ++i)
#pragma unroll
        for (int j = 0; j < 4; ++j) {
            const int n = n0 + wn + j * 16 + lane15;
#pragma unroll
            for (int r = 0; r < 4; ++r) {
                const int m = m0 + wm + i * 16 + (l >> 4) * 4 + r;
                ex[xbase + (size_t)m * D_ + n] = f2bf(acc[i][j][r] + biasv[j]);
            }
        }
}

// ---------------------------------------------------------------------------
// Combine: out[b,s,:] = sum_e aff[b,e,s] * ex[bl,e,map[b,s,e],:]   (fp32 out)
// ---------------------------------------------------------------------------
__global__ __launch_bounds__(256) void combine_k(
    const unsigned short* __restrict__ ex, const float* __restrict__ aff,
    const int* __restrict__ map, float* __restrict__ out, int b_base)
{
    const int t = threadIdx.x;
    const int w = t >> 6, l = t & 63;
    const size_t tokl = (size_t)blockIdx.x * 4 + w;   // local token within chunk
    const int bl = (int)(tokl >> 13);
    const int s  = (int)(tokl & (S_ - 1));
    const int b  = b_base + bl;

    int jv = -1; float gv = 0.f;
    if (l < 16) {
        jv = map[((size_t)b * S_ + s) * E_ + l];
        gv = aff[((size_t)b * E_ + l) * S_ + s];
    }
    float acc[8] = {0.f, 0.f, 0.f, 0.f, 0.f, 0.f, 0.f, 0.f};
#pragma unroll
    for (int e = 0; e < E_; ++e) {
        const int je = __shfl(jv, e);
        if (je < 0) continue;
        const float ge = __shfl(gv, e);
        const unsigned short* row = ex + (((size_t)bl * E_ + e) * KROW_ + je) * D_ + l * 8;
        short8 v = *(const short8*)row;
#pragma unroll
        for (int q = 0; q < 8; ++q) acc[q] += ge * bf2f((unsigned short)v[q]);
    }
    float* orow = out + ((size_t)b * S_ + s) * D_ + l * 8;
    float4 o0 = {acc[0], acc[1], acc[2], acc[3]};
    float4 o1 = {acc[4], acc[5], acc[6], acc[7]};
    ((float4*)orow)[0] = o0;
    ((float4*)orow)[1] = o1;
}

// ---------------------------------------------------------------------------
extern "C" void kernel_launch(void* const* d_in, const int* in_sizes, int n_in,
                              void* d_out, int out_size, void* d_ws, size_t ws_size,
                              hipStream_t stream) {
    const float* x  = (const float*)d_in[0];
    const float* gw = (const float*)d_in[1];
    const float* w1 = (const float*)d_in[2];
    const float* b1 = (const float*)d_in[3];
    const float* w2 = (const float*)d_in[4];
    const float* b2 = (const float*)d_in[5];
    float* out = (float*)d_out;
    char* ws = (char*)d_ws;

    size_t off = 0;
    float* aff = (float*)(ws + off);          off += (size_t)B_ * E_ * S_ * 4;       // 4 MB
    int* idxb  = (int*)(ws + off);            off += (size_t)B_ * E_ * KROW_ * 4;    // 0.5 MB
    int* map   = (int*)(ws + off);            off += (size_t)B_ * S_ * E_ * 4;       // 4 MB
    unsigned short* w1t = (unsigned short*)(ws + off); off += (size_t)E_ * DFF_ * D_ * 2; // 8 MB
    unsigned short* w2t = (unsigned short*)(ws + off); off += (size_t)E_ * D_ * DFF_ * 2; // 8 MB
    unsigned short* xb  = (unsigned short*)(ws + off); off += (size_t)B_ * S_ * D_ * 2;   // 64 MB
    const size_t fixed = off;
    const size_t per_b_h  = (size_t)E_ * KROW_ * DFF_ * 2;   // 16 MB
    const size_t per_b_ex = (size_t)E_ * KROW_ * D_ * 2;     // 16 MB
    const size_t per_b = per_b_h + per_b_ex;

    int bchunk = 1;
    if (ws_size > fixed + per_b) {
        size_t m = (ws_size - fixed) / per_b;
        bchunk = (int)(m > (size_t)B_ ? (size_t)B_ : m);
        if (bchunk < 1) bchunk = 1;
    }
    unsigned short* h  = (unsigned short*)(ws + fixed);
    unsigned short* ex = (unsigned short*)(ws + fixed + (size_t)bchunk * per_b_h);

    hipMemsetAsync(map, 0xFF, (size_t)B_ * S_ * E_ * 4, stream);
    cvt_x_k<<<dim3((B_ * S_ * D_ / 8 + 255) / 256), dim3(256), 0, stream>>>(
        x, xb, B_ * S_ * D_ / 8);
    transpose_w_k<<<dim3(16, 16, 32), dim3(32, 8, 1), 0, stream>>>(w1, w2, w1t, w2t);
    router_k<<<dim3((B_ * S_) / 64), dim3(512), 0, stream>>>(x, gw, aff);
    topk_k<<<dim3(B_ * E_), dim3(1024), 0, stream>>>(aff, idxb, map);

    for (int b0 = 0; b0 < B_; b0 += bchunk) {
        const int bc = (b0 + bchunk <= B_) ? bchunk : (B_ - b0);
        gemm1_k<<<dim3(KROW_ / 128, DFF_ / 128, bc * E_), dim3(256), 0, stream>>>(
            xb, w1t, b1, idxb, h, b0);
        gemm2_k<<<dim3(KROW_ / 128, D_ / 128, bc * E_), dim3(256), 0, stream>>>(
            h, w2t, b2, ex);
        combine_k<<<dim3(bc * (S_ / 4)), dim3(256), 0, stream>>>(ex, aff, map, out, b0);
    }
}

// Round 5
// 573.894 us; speedup vs baseline: 1.0543x; 1.0543x over previous
//
#include <hip/hip_runtime.h>
#include <hip/hip_bf16.h>

typedef __attribute__((ext_vector_type(8))) short short8;
typedef __attribute__((ext_vector_type(4))) float floatx4;
typedef __attribute__((ext_vector_type(4))) unsigned short ushort4_t;

#define B_    8
#define S_    8192
#define D_    512
#define E_    16
#define DFF_  512
#define KROW_ 1024   // tokens per expert (capacity)

__device__ __forceinline__ float bf2f(unsigned short u) {
    return __uint_as_float(((unsigned int)u) << 16);
}
__device__ __forceinline__ unsigned short f2bf(float f) {
    unsigned int u = __float_as_uint(f);
    u += 0x7FFFu + ((u >> 16) & 1u);
    return (unsigned short)(u >> 16);
}
__device__ __forceinline__ float gelu_tanh(float v) {
    // jax.nn.gelu(approximate=True): 0.5*x*(1+tanh(z)) == x*sigmoid(2z) exactly.
    const float t = v * fmaf(0.0713548065f, v * v, 1.5957691216057308f);
    return v * __builtin_amdgcn_rcpf(1.0f + __expf(-t));
}

#define GLD16(g, l) __builtin_amdgcn_global_load_lds( \
    (const __attribute__((address_space(1))) void*)(g), \
    (__attribute__((address_space(3))) void*)(l), 16, 0, 0)

// XCD-chunked bijective remap (T1): hardware assigns consecutive linear block
// ids round-robin across 8 XCDs. Remap so each XCD owns a CONTIGUOUS chunk of
// work ordered (e, bl, m0, n0) -> 2 experts' weights (1 MB) stay resident in
// that XCD's 4 MB L2, and the 4 n0-replicas of each A-tile are rank-adjacent.
// total = 32 * gridDim.z (always divisible by 8) -> bijective.
__device__ __forceinline__ void xcd_remap(int& m0i, int& n0i, int& bl, int& e) {
    const int total = (int)(gridDim.x * gridDim.y * gridDim.z);
    const int chunk = total >> 3;
    const int wgid  = (int)(blockIdx.x + gridDim.x * (blockIdx.y + gridDim.y * blockIdx.z));
    const int widx  = (wgid & 7) * chunk + (wgid >> 3);
    n0i = widx & 3;            // n0 fastest: 4 replicas of an A-tile co-resident
    m0i = (widx >> 2) & 7;
    const int tz  = widx >> 5;
    const int nbl = (int)(gridDim.z >> 4);
    bl = tz % nbl;
    e  = tz / nbl;
}

// ---------------------------------------------------------------------------
// x fp32 -> xb bf16 (flat, coalesced, 16B stores)
// ---------------------------------------------------------------------------
__global__ __launch_bounds__(256) void cvt_x_k(
    const float* __restrict__ x, unsigned short* __restrict__ xb, int n8)
{
    int i = blockIdx.x * 256 + threadIdx.x;
    if (i >= n8) return;
    float4 va = ((const float4*)x)[2 * i];
    float4 vb = ((const float4*)x)[2 * i + 1];
    short8 o;
    o[0] = (short)f2bf(va.x); o[1] = (short)f2bf(va.y);
    o[2] = (short)f2bf(va.z); o[3] = (short)f2bf(va.w);
    o[4] = (short)f2bf(vb.x); o[5] = (short)f2bf(vb.y);
    o[6] = (short)f2bf(vb.z); o[7] = (short)f2bf(vb.w);
    ((short8*)xb)[i] = o;
}

// ---------------------------------------------------------------------------
// w1[e][D][DFF] fp32 -> w1t[e][DFF][D] bf16 ; w2[e][DFF][D] fp32 -> w2t[e][D][DFF] bf16
// ---------------------------------------------------------------------------
__global__ __launch_bounds__(256) void transpose_w_k(
    const float* __restrict__ w1, const float* __restrict__ w2,
    unsigned short* __restrict__ w1t, unsigned short* __restrict__ w2t)
{
    __shared__ unsigned short tile[32][33];
    const int e = blockIdx.z & 15;
    const float*    src = (blockIdx.z < 16) ? w1 : w2;
    unsigned short* dst = (blockIdx.z < 16) ? w1t : w2t;
    const int x0 = blockIdx.x * 32, y0 = blockIdx.y * 32;
    const int tx = threadIdx.x, ty = threadIdx.y;   // block (32,8)
    const size_t base = (size_t)e * 512 * 512;
#pragma unroll
    for (int i = 0; i < 4; ++i)
        tile[ty + 8 * i][tx] = f2bf(src[base + (size_t)(y0 + ty + 8 * i) * 512 + x0 + tx]);
    __syncthreads();
#pragma unroll
    for (int i = 0; i < 4; ++i)
        dst[base + (size_t)(x0 + ty + 8 * i) * 512 + y0 + tx] = tile[tx][ty + 8 * i];
}

// ---------------------------------------------------------------------------
// Router, 8 lanes per token; aff bitwise identical to 1-thread/token version.
// ---------------------------------------------------------------------------
__global__ __launch_bounds__(512) void router_k(
    const float* __restrict__ x,   // [B,S,D]
    const float* __restrict__ gw,  // [D,E]
    float* __restrict__ aff)       // [B,E,S]
{
    __shared__ float gws[D_ * E_];   // 32 KB
    const int t = threadIdx.x;
    for (int i = t; i < D_ * E_; i += 512) gws[i] = gw[i];
    __syncthreads();

    const int lane = t & 63;
    const int sub  = lane & 7;                    // expert pair id
    const int tok  = blockIdx.x * 64 + (t >> 3);
    const float4* xr = (const float4*)(x + (size_t)tok * D_);

    float acc0 = 0.f, acc1 = 0.f;
#pragma unroll 4
    for (int d8 = 0; d8 < D_ / 8; ++d8) {
        const float4 va = xr[2 * d8];
        const float4 vb = xr[2 * d8 + 1];
#pragma unroll
        for (int q = 0; q < 8; ++q) {
            const float xv = (q < 4) ? (&va.x)[q] : (&vb.x)[q - 4];
            const float2 gv = *(const float2*)&gws[(d8 * 8 + q) * E_ + 2 * sub];
            acc0 = fmaf(xv, gv.x, acc0);
            acc1 = fmaf(xv, gv.y, acc1);
        }
    }

    const int base = lane & 56;                   // first lane of my 8-lane group
    float accs[E_];
#pragma unroll
    for (int i = 0; i < 8; ++i) {
        accs[2 * i]     = __shfl(acc0, base + i);
        accs[2 * i + 1] = __shfl(acc1, base + i);
    }
    float mx = accs[0];
#pragma unroll
    for (int e = 1; e < E_; ++e) mx = fmaxf(mx, accs[e]);   // order-exact
    const float e0v = expf(acc0 - mx);
    const float e1v = expf(acc1 - mx);
    float sm = 0.f;
#pragma unroll
    for (int i = 0; i < 8; ++i) {                 // sum in original e=0..15 order
        sm += __shfl(e0v, base + i);
        sm += __shfl(e1v, base + i);
    }
    const float inv = 1.f / sm;
    const int b = tok >> 13, s = tok & (S_ - 1);
    aff[((size_t)b * E_ + 2 * sub) * S_ + s]     = e0v * inv;
    aff[((size_t)b * E_ + 2 * sub + 1) * S_ + s] = e1v * inv;
}

// ---------------------------------------------------------------------------
// Top-k per (b,e): exact k-th-largest via 4-level MSB radix select.
// 16-way privatized histogram (one copy per wave) — softmax values cluster
// into few exponent bins at level 0; 4 copies had ~2048 serialized
// same-address LDS atomics per copy, 16 copies cut that 4x.
// ---------------------------------------------------------------------------
__global__ __launch_bounds__(1024) void topk_k(
    const float* __restrict__ aff, int* __restrict__ idxb, int* __restrict__ map)
{
    __shared__ unsigned int keys[S_];        // 32 KB
    __shared__ unsigned int hist[16][257];   // 16 privatized copies (+pad) ~16.4 KB
    __shared__ unsigned int wsum[16];
    __shared__ unsigned int sh_b, sh_above, sh_ctr;

    const int b = blockIdx.x >> 4, e = blockIdx.x & 15;
    const float* a = aff + ((size_t)b * E_ + e) * S_;
    const int t = threadIdx.x;
    const int lane = t & 63, wid = t >> 6;

    for (int i = t; i < S_; i += 1024) keys[i] = __float_as_uint(a[i]);
    if (t == 0) sh_ctr = 0;
    for (int i = t; i < 16 * 257; i += 1024) ((unsigned int*)hist)[i] = 0;
    __syncthreads();

    unsigned int prefix = 0, need = KROW_;
#pragma unroll
    for (int lev = 0; lev < 4; ++lev) {
        const int shift = (lev == 0) ? 23 : (lev == 1) ? 15 : (lev == 2) ? 7 : 0;
        const unsigned int fmask = (lev == 3) ? 127u : 255u;
        const int sw = shift + ((lev == 3) ? 7 : 8);
        const unsigned int mask_hi = 0xFFFFFFFFu << sw;

        for (int i = t; i < S_; i += 1024) {
            unsigned int k = keys[i];
            if ((k & mask_hi) == prefix)
                atomicAdd(&hist[wid][(k >> shift) & fmask], 1u);
        }
        __syncthreads();

        // single-wave suffix scan over 256 bins: lane l owns bins 4l..4l+3
        if (t < 64) {
            unsigned int s0 = 0, s1 = 0, s2 = 0, s3 = 0;
#pragma unroll
            for (int c = 0; c < 16; ++c) {
                s0 += hist[c][4 * t + 0]; s1 += hist[c][4 * t + 1];
                s2 += hist[c][4 * t + 2]; s3 += hist[c][4 * t + 3];
            }
            const unsigned int v3 = s3, v2 = s2 + v3, v1 = s1 + v2, v0 = s0 + v1;
            const unsigned int G = v0;
            unsigned int T = v0;
#pragma unroll
            for (int off = 1; off < 64; off <<= 1) {
                unsigned int u = (unsigned int)__shfl_down((int)T, off);
                if (lane + off < 64) T += u;
            }
            const unsigned int R = T - G;
            unsigned int Sv[5];
            Sv[0] = T; Sv[1] = v1 + R; Sv[2] = v2 + R; Sv[3] = v3 + R; Sv[4] = R;
#pragma unroll
            for (int k2 = 0; k2 < 4; ++k2)
                if (Sv[k2] >= need && Sv[k2 + 1] < need) {
                    sh_b = (unsigned int)(4 * t + k2);
                    sh_above = Sv[k2 + 1];
                }
        }
        __syncthreads();
        prefix |= sh_b << shift;
        need   -= sh_above;
        if (lev < 3) {
            for (int i = t; i < 16 * 257; i += 1024) ((unsigned int*)hist)[i] = 0;
        }
        __syncthreads();
    }

    const unsigned int thr = prefix;        // exact k-th largest key
    const unsigned int need_eq = need;      // # ties (==thr) to keep
    const unsigned int m_gt = KROW_ - need_eq;

    int* idxg = idxb + ((size_t)b * E_ + e) * KROW_;
    for (int i = t; i < S_; i += 1024) {
        unsigned int k = keys[i];
        if (k > thr) {
            unsigned int slot = atomicAdd(&sh_ctr, 1u);
            idxg[slot] = i;
            map[((size_t)b * S_ + i) * E_ + e] = (int)slot;
        }
    }
    // stable tie ranking: hierarchical scan of per-thread tie counts
    unsigned int lt = 0;
    const int i0 = t * 8;
#pragma unroll
    for (int q = 0; q < 8; ++q) lt += (keys[i0 + q] == thr);
    unsigned int incl = lt;
#pragma unroll
    for (int off = 1; off < 64; off <<= 1) {
        unsigned int u = (unsigned int)__shfl_up((int)incl, off);
        if (lane >= off) incl += u;
    }
    if (lane == 63) wsum[wid] = incl;
    __syncthreads();
    if (t < 16) {
        unsigned int wv = wsum[t];
        unsigned int ex = wv;
#pragma unroll
        for (int off = 1; off < 16; off <<= 1) {
            unsigned int u = (unsigned int)__shfl_up((int)ex, off);
            if (lane >= off) ex += u;
        }
        wsum[t] = ex - wv;
    }
    __syncthreads();
    unsigned int r = (incl - lt) + wsum[wid];
#pragma unroll
    for (int q = 0; q < 8; ++q) {
        if (keys[i0 + q] == thr) {
            if (r < need_eq) {
                idxg[m_gt + r] = i0 + q;
                map[((size_t)b * S_ + (i0 + q)) * E_ + e] = (int)(m_gt + r);
            }
            r++;
        }
    }
}

// ---------------------------------------------------------------------------
// GEMM1: h[bl,e,j,:] = gelu( xb[b, idx[b,e,j], :] @ w1t[e]^T + b1[e] )
// 128x128 tile, BK=32, dbuf prefetch + XCD-chunked block remap (T1).
// ---------------------------------------------------------------------------
__global__ __launch_bounds__(256) void gemm1_k(
    const unsigned short* __restrict__ xb,   // [B,S,D] bf16
    const unsigned short* __restrict__ w1t,  // [E,DFF,D] bf16 (B^T: [N,K])
    const float* __restrict__ b1,            // [E,DFF] fp32
    const int* __restrict__ idxb,            // [B,E,KROW]
    unsigned short* __restrict__ h,          // [bchunk,E,KROW,DFF] bf16
    int b_base)
{
    __shared__ unsigned short As[2][128 * 32];
    __shared__ unsigned short Bs[2][128 * 32];
    int m0i, n0i, bl, e;
    xcd_remap(m0i, n0i, bl, e);
    const int b  = b_base + bl;
    const int m0 = m0i * 128;
    const int n0 = n0i * 128;
    const int t = threadIdx.x;
    const int w = t >> 6, l = t & 63;
    const int r0 = t >> 2, c0 = (t & 3) * 8;

    const int* idxg = idxb + ((size_t)b * E_ + e) * KROW_;
    const int s0 = idxg[m0 + r0];
    const int s1 = idxg[m0 + 64 + r0];
    const unsigned short* a0 = xb + ((size_t)b * S_ + s0) * D_ + c0;
    const unsigned short* a1 = xb + ((size_t)b * S_ + s1) * D_ + c0;
    const unsigned short* g0 = w1t + ((size_t)e * DFF_ + n0 + r0) * D_ + c0;
    const unsigned short* g1 = w1t + ((size_t)e * DFF_ + n0 + 64 + r0) * D_ + c0;

    floatx4 acc[4][4];
#pragma unroll
    for (int i = 0; i < 4; ++i)
#pragma unroll
        for (int j = 0; j < 4; ++j) acc[i][j] = (floatx4){0.f, 0.f, 0.f, 0.f};

    const int wm = (w >> 1) * 64, wn = (w & 1) * 64;
    const int lane15 = l & 15, lk = (l >> 4) * 8;

    {
        unsigned short* asd = &As[0][w * 512];
        unsigned short* bsd = &Bs[0][w * 512];
        GLD16(a0, asd); GLD16(a1, asd + 2048);
        GLD16(g0, bsd); GLD16(g1, bsd + 2048);
    }
    __syncthreads();

#pragma unroll
    for (int kt = 0; kt < D_ / 32; ++kt) {
        const int cur = kt & 1;
        if (kt + 1 < D_ / 32) {
            const int k1 = (kt + 1) * 32;
            unsigned short* asd = &As[cur ^ 1][w * 512];
            unsigned short* bsd = &Bs[cur ^ 1][w * 512];
            GLD16(a0 + k1, asd); GLD16(a1 + k1, asd + 2048);
            GLD16(g0 + k1, bsd); GLD16(g1 + k1, bsd + 2048);
        }
        short8 af[4], bf[4];
#pragma unroll
        for (int i = 0; i < 4; ++i) af[i] = *(const short8*)&As[cur][(wm + i * 16 + lane15) * 32 + lk];
#pragma unroll
        for (int j = 0; j < 4; ++j) bf[j] = *(const short8*)&Bs[cur][(wn + j * 16 + lane15) * 32 + lk];
#pragma unroll
        for (int i = 0; i < 4; ++i)
#pragma unroll
            for (int j = 0; j < 4; ++j)
                acc[i][j] = __builtin_amdgcn_mfma_f32_16x16x32_bf16(af[i], bf[j], acc[i][j], 0, 0, 0);
        __syncthreads();
    }

    float biasv[4];
#pragma unroll
    for (int j = 0; j < 4; ++j) biasv[j] = b1[e * DFF_ + n0 + wn + j * 16 + lane15];

    const size_t hbase = ((size_t)bl * E_ + e) * KROW_ * DFF_;
#pragma unroll
    for (int i = 0; i < 4; ++i)
#pragma unroll
        for (int j = 0; j < 4; ++j) {
            const int n = n0 + wn + j * 16 + lane15;
#pragma unroll
            for (int r = 0; r < 4; ++r) {
                const int m = m0 + wm + i * 16 + (l >> 4) * 4 + r;
                h[hbase + (size_t)m * DFF_ + n] = f2bf(gelu_tanh(acc[i][j][r] + biasv[j]));
            }
        }
}

// ---------------------------------------------------------------------------
// GEMM2: ex[bl,e,j,:] = h[bl,e,j,:] @ w2t[e]^T + b2[e]  (dbuf + T1 remap)
// ---------------------------------------------------------------------------
__global__ __launch_bounds__(256) void gemm2_k(
    const unsigned short* __restrict__ h,    // [bchunk,E,KROW,DFF] bf16
    const unsigned short* __restrict__ w2t,  // [E,D,DFF] bf16 (B^T: [N,K])
    const float* __restrict__ b2,            // [E,D] fp32
    unsigned short* __restrict__ ex)         // [bchunk,E,KROW,D] bf16
{
    __shared__ unsigned short As[2][128 * 32];
    __shared__ unsigned short Bs[2][128 * 32];
    int m0i, n0i, bl, e;
    xcd_remap(m0i, n0i, bl, e);
    const int m0 = m0i * 128;
    const int n0 = n0i * 128;
    const int t = threadIdx.x;
    const int w = t >> 6, l = t & 63;
    const int r0 = t >> 2, c0 = (t & 3) * 8;

    const unsigned short* a0 = h + (((size_t)bl * E_ + e) * KROW_ + m0 + r0) * DFF_ + c0;
    const unsigned short* a1 = h + (((size_t)bl * E_ + e) * KROW_ + m0 + 64 + r0) * DFF_ + c0;
    const unsigned short* g0 = w2t + ((size_t)e * D_ + n0 + r0) * DFF_ + c0;
    const unsigned short* g1 = w2t + ((size_t)e * D_ + n0 + 64 + r0) * DFF_ + c0;

    floatx4 acc[4][4];
#pragma unroll
    for (int i = 0; i < 4; ++i)
#pragma unroll
        for (int j = 0; j < 4; ++j) acc[i][j] = (floatx4){0.f, 0.f, 0.f, 0.f};

    const int wm = (w >> 1) * 64, wn = (w & 1) * 64;
    const int lane15 = l & 15, lk = (l >> 4) * 8;

    {
        unsigned short* asd = &As[0][w * 512];
        unsigned short* bsd = &Bs[0][w * 512];
        GLD16(a0, asd); GLD16(a1, asd + 2048);
        GLD16(g0, bsd); GLD16(g1, bsd + 2048);
    }
    __syncthreads();

#pragma unroll
    for (int kt = 0; kt < DFF_ / 32; ++kt) {
        const int cur = kt & 1;
        if (kt + 1 < DFF_ / 32) {
            const int k1 = (kt + 1) * 32;
            unsigned short* asd = &As[cur ^ 1][w * 512];
            unsigned short* bsd = &Bs[cur ^ 1][w * 512];
            GLD16(a0 + k1, asd); GLD16(a1 + k1, asd + 2048);
            GLD16(g0 + k1, bsd); GLD16(g1 + k1, bsd + 2048);
        }
        short8 af[4], bf[4];
#pragma unroll
        for (int i = 0; i < 4; ++i) af[i] = *(const short8*)&As[cur][(wm + i * 16 + lane15) * 32 + lk];
#pragma unroll
        for (int j = 0; j < 4; ++j) bf[j] = *(const short8*)&Bs[cur][(wn + j * 16 + lane15) * 32 + lk];
#pragma unroll
        for (int i = 0; i < 4; ++i)
#pragma unroll
            for (int j = 0; j < 4; ++j)
                acc[i][j] = __builtin_amdgcn_mfma_f32_16x16x32_bf16(af[i], bf[j], acc[i][j], 0, 0, 0);
        __syncthreads();
    }

    float biasv[4];
#pragma unroll
    for (int j = 0; j < 4; ++j) biasv[j] = b2[e * D_ + n0 + wn + j * 16 + lane15];

    const size_t xbase = ((size_t)bl * E_ + e) * KROW_ * D_;
#pragma unroll
    for (int i = 0; i < 4; ++i)
#pragma unroll
        for (int j = 0; j < 4; ++j) {
            const int n = n0 + wn + j * 16 + lane15;
#pragma unroll
            for (int r = 0; r < 4; ++r) {
                const int m = m0 + wm + i * 16 + (l >> 4) * 4 + r;
                ex[xbase + (size_t)m * D_ + n] = f2bf(acc[i][j][r] + biasv[j]);
            }
        }
}

// ---------------------------------------------------------------------------
// Combine: out[b,s,:] = sum_e aff[b,e,s] * ex[bl,e,map[b,s,e],:]   (fp32 out)
// ---------------------------------------------------------------------------
__global__ __launch_bounds__(256) void combine_k(
    const unsigned short* __restrict__ ex, const float* __restrict__ aff,
    const int* __restrict__ map, float* __restrict__ out, int b_base)
{
    const int t = threadIdx.x;
    const int w = t >> 6, l = t & 63;
    const size_t tokl = (size_t)blockIdx.x * 4 + w;   // local token within chunk
    const int bl = (int)(tokl >> 13);
    const int s  = (int)(tokl & (S_ - 1));
    const int b  = b_base + bl;

    int jv = -1; float gv = 0.f;
    if (l < 16) {
        jv = map[((size_t)b * S_ + s) * E_ + l];
        gv = aff[((size_t)b * E_ + l) * S_ + s];
    }
    float acc[8] = {0.f, 0.f, 0.f, 0.f, 0.f, 0.f, 0.f, 0.f};
#pragma unroll
    for (int e = 0; e < E_; ++e) {
        const int je = __shfl(jv, e);
        if (je < 0) continue;
        const float ge = __shfl(gv, e);
        const unsigned short* row = ex + (((size_t)bl * E_ + e) * KROW_ + je) * D_ + l * 8;
        short8 v = *(const short8*)row;
#pragma unroll
        for (int q = 0; q < 8; ++q) acc[q] += ge * bf2f((unsigned short)v[q]);
    }
    float* orow = out + ((size_t)b * S_ + s) * D_ + l * 8;
    float4 o0 = {acc[0], acc[1], acc[2], acc[3]};
    float4 o1 = {acc[4], acc[5], acc[6], acc[7]};
    ((float4*)orow)[0] = o0;
    ((float4*)orow)[1] = o1;
}

// ---------------------------------------------------------------------------
extern "C" void kernel_launch(void* const* d_in, const int* in_sizes, int n_in,
                              void* d_out, int out_size, void* d_ws, size_t ws_size,
                              hipStream_t stream) {
    const float* x  = (const float*)d_in[0];
    const float* gw = (const float*)d_in[1];
    const float* w1 = (const float*)d_in[2];
    const float* b1 = (const float*)d_in[3];
    const float* w2 = (const float*)d_in[4];
    const float* b2 = (const float*)d_in[5];
    float* out = (float*)d_out;
    char* ws = (char*)d_ws;

    size_t off = 0;
    float* aff = (float*)(ws + off);          off += (size_t)B_ * E_ * S_ * 4;       // 4 MB
    int* idxb  = (int*)(ws + off);            off += (size_t)B_ * E_ * KROW_ * 4;    // 0.5 MB
    int* map   = (int*)(ws + off);            off += (size_t)B_ * S_ * E_ * 4;       // 4 MB
    unsigned short* w1t = (unsigned short*)(ws + off); off += (size_t)E_ * DFF_ * D_ * 2; // 8 MB
    unsigned short* w2t = (unsigned short*)(ws + off); off += (size_t)E_ * D_ * DFF_ * 2; // 8 MB
    unsigned short* xb  = (unsigned short*)(ws + off); off += (size_t)B_ * S_ * D_ * 2;   // 64 MB
    const size_t fixed = off;
    const size_t per_b_h  = (size_t)E_ * KROW_ * DFF_ * 2;   // 16 MB
    const size_t per_b_ex = (size_t)E_ * KROW_ * D_ * 2;     // 16 MB
    const size_t per_b = per_b_h + per_b_ex;

    int bchunk = 1;
    if (ws_size > fixed + per_b) {
        size_t m = (ws_size - fixed) / per_b;
        bchunk = (int)(m > (size_t)B_ ? (size_t)B_ : m);
        if (bchunk < 1) bchunk = 1;
    }
    unsigned short* h  = (unsigned short*)(ws + fixed);
    unsigned short* ex = (unsigned short*)(ws + fixed + (size_t)bchunk * per_b_h);

    hipMemsetAsync(map, 0xFF, (size_t)B_ * S_ * E_ * 4, stream);
    cvt_x_k<<<dim3((B_ * S_ * D_ / 8 + 255) / 256), dim3(256), 0, stream>>>(
        x, xb, B_ * S_ * D_ / 8);
    transpose_w_k<<<dim3(16, 16, 32), dim3(32, 8, 1), 0, stream>>>(w1, w2, w1t, w2t);
    router_k<<<dim3((B_ * S_) / 64), dim3(512), 0, stream>>>(x, gw, aff);
    topk_k<<<dim3(B_ * E_), dim3(1024), 0, stream>>>(aff, idxb, map);

    for (int b0 = 0; b0 < B_; b0 += bchunk) {
        const int bc = (b0 + bchunk <= B_) ? bchunk : (B_ - b0);
        gemm1_k<<<dim3(KROW_ / 128, DFF_ / 128, bc * E_), dim3(256), 0, stream>>>(
            xb, w1t, b1, idxb, h, b0);
        gemm2_k<<<dim3(KROW_ / 128, D_ / 128, bc * E_), dim3(256), 0, stream>>>(
            h, w2t, b2, ex);
        combine_k<<<dim3(bc * (S_ / 4)), dim3(256), 0, stream>>>(ex, aff, map, out, b0);
    }
}